// Round 1
// baseline (17559.419 us; speedup 1.0000x reference)
//
#include <hip/hip_runtime.h>

#define NTT 256
#define NCC 128

__device__ __forceinline__ float dfh_tanh_f(float v){ return tanhf(v)*0.98f + 0.02f*v; }
__device__ __forceinline__ float dfh_sig_f(float v){ return 0.98f/(1.f+expf(-v)) + 0.02f*v; }

// ---------------- build c-layer input + dense + tanh; zero skip -------------
__global__ __launch_bounds__(256) void k_build_c(
    const float* __restrict__ times, const float* __restrict__ times_in,
    const float* __restrict__ i2nc, const float* __restrict__ i2c,
    const float* __restrict__ dw, const float* __restrict__ db,
    float* __restrict__ x, float* __restrict__ skip)
{
  int gid = blockIdx.x*256 + threadIdx.x;          // t*128 + c
  if (gid >= NTT*NCC) return;
  int c = gid & 127, t = gid >> 7;
  float v0 = i2nc[c*NTT + t];
  float v1 = i2c [c*NTT + t];
  float v2 = times[t];
  float v3 = times_in[c];
  #pragma unroll
  for (int f=0; f<16; ++f){
    float a = v0*dw[f] + v1*dw[16+f] + v2*dw[32+f] + v3*dw[48+f] + db[f];
    x[gid*16+f]    = dfh_tanh_f(a);
    skip[gid*16+f] = 0.f;
  }
}

// ---------------- h-layer dense + tanh; zero skip ---------------------------
__global__ __launch_bounds__(256) void k_build_h(
    const float* __restrict__ hinp, const float* __restrict__ dw,
    const float* __restrict__ db, float* __restrict__ x, float* __restrict__ skip)
{
  int gid = blockIdx.x*256 + threadIdx.x;          // c*256 + t
  if (gid >= NCC*NTT) return;
  const float* in = hinp + gid*16;
  float iv[16];
  #pragma unroll
  for (int i=0;i<16;i++) iv[i]=in[i];
  #pragma unroll
  for (int f=0; f<16; ++f){
    float a = db[f];
    #pragma unroll
    for (int i=0;i<16;i++) a += iv[i]*dw[i*16+f];
    x[gid*16+f]    = dfh_tanh_f(a);
    skip[gid*16+f] = 0.f;
  }
}

// ---------------- gated dilated conv: g = dfh_tanh(conv1)*dfh_sigmoid(conv2)
// x: [H][W][16], g: [H][W][8].  pad H by 2 both sides, W end-padded (zeros).
__global__ __launch_bounds__(256) void k_gate(
    const float* __restrict__ x, float* __restrict__ g,
    const float* __restrict__ wy1, const float* __restrict__ by1,
    const float* __restrict__ wy2, const float* __restrict__ by2,
    int H, int W, int dil)
{
  int gid = blockIdx.x*256 + threadIdx.x;
  int f  = gid & 7;
  int hw = gid >> 3;
  if (hw >= H*W) return;
  int w = hw % W, h = hw / W;
  float a1 = by1[f], a2 = by2[f];
  for (int kh=0; kh<5; ++kh){
    int hh = h + kh - 2;
    if (hh < 0 || hh >= H) continue;
    const float* xrow = x + hh*W*16;
    for (int kw=0; kw<8; ++kw){
      int ww = w + dil*kw;
      if (ww >= W) break;
      const float4* xp = reinterpret_cast<const float4*>(xrow + ww*16);
      const float* w1 = wy1 + (kh*8+kw)*128 + f;   // [kh][kw][ci][f], f stride 1
      const float* w2 = wy2 + (kh*8+kw)*128 + f;
      #pragma unroll
      for (int q=0; q<4; ++q){
        float4 xv = xp[q];
        a1 += xv.x*w1[(q*4+0)*8] + xv.y*w1[(q*4+1)*8] + xv.z*w1[(q*4+2)*8] + xv.w*w1[(q*4+3)*8];
        a2 += xv.x*w2[(q*4+0)*8] + xv.y*w2[(q*4+1)*8] + xv.z*w2[(q*4+2)*8] + xv.w*w2[(q*4+3)*8];
      }
    }
  }
  g[hw*8+f] = dfh_tanh_f(a1)*dfh_sig_f(a2);
}

// ---------------- z-conv (dil=1) + residual updates: skip+=z, x+=z ----------
// g: [H][W][8], wz: [kh][kw][fi][fo] (5,8,8,16)
__global__ __launch_bounds__(256) void k_zres(
    const float* __restrict__ g, float* __restrict__ x, float* __restrict__ skip,
    const float* __restrict__ wz, const float* __restrict__ bz, int H, int W)
{
  int gid = blockIdx.x*256 + threadIdx.x;
  int fo = gid & 15;
  int hw = gid >> 4;
  if (hw >= H*W) return;
  int w = hw % W, h = hw / W;
  float acc = bz[fo];
  for (int kh=0; kh<5; ++kh){
    int hh = h + kh - 2;
    if (hh < 0 || hh >= H) continue;
    const float* grow = g + hh*W*8;
    for (int kw=0; kw<8; ++kw){
      int ww = w + kw;
      if (ww >= W) break;
      const float4* gp = reinterpret_cast<const float4*>(grow + ww*8);
      const float* wp = wz + (kh*8+kw)*128 + fo;   // fi stride 16
      float4 g0 = gp[0], g1 = gp[1];
      acc += g0.x*wp[0]   + g0.y*wp[16]  + g0.z*wp[32]  + g0.w*wp[48]
           + g1.x*wp[64]  + g1.y*wp[80]  + g1.z*wp[96]  + g1.w*wp[112];
    }
  }
  int idx = hw*16 + fo;
  skip[idx] += acc;
  x[idx]    += acc;
}

// ---------------- cout = dfh_tanh(skip) -------------------------------------
__global__ __launch_bounds__(256) void k_dtanh(const float* __restrict__ s,
                                               float* __restrict__ o, int n)
{
  int i = blockIdx.x*256 + threadIdx.x;
  if (i < n) o[i] = dfh_tanh_f(s[i]);
}

// ---------------- stage C, DFT #1: length-128 over channel pairs ------------
// cout: [t][c][16]  ->  cft[f][c][t] = Re(fftshift(FFT128(mult*s)))[c]
__global__ __launch_bounds__(256) void k_dft_c1(const float* __restrict__ cout,
                                                float* __restrict__ cft)
{
  __shared__ float ctab[128], stab[128];
  int tid = threadIdx.x;
  if (tid < 128){
    float ang = (float)tid * (6.283185307179586f/128.f);
    ctab[tid] = cosf(ang); stab[tid] = sinf(ang);
  }
  __syncthreads();
  int gid = blockIdx.x*256 + tid;                  // f*32768 + c*256 + t
  int t = gid & 255, c = (gid>>8)&127, f = gid>>15;
  int j = (c + 64) & 127;
  const float* base = cout + t*(128*16) + f;
  float acc = 0.5f*base[0];                        // k=0 term (mult=0.5, m=0)
  for (int k=1; k<64; ++k){
    float re = base[(2*k)*16], im = base[(2*k+1)*16];
    int m = (j*k) & 127;
    acc += re*ctab[m] + im*stab[m];
  }
  cft[(f*128 + c)*256 + t] = acc;
}

// ---------------- stage C, DFT #2 + hilbert/conj/mask collapse --------------
// cft[f][c][t] -> hinp[c][tau][f] with tau=2k (Re), 2k+1 (Im), k<128
__global__ __launch_bounds__(256) void k_dft_c2(const float* __restrict__ cft,
                                                const float* __restrict__ times,
                                                float* __restrict__ hinp)
{
  __shared__ float ctab[256], stab[256];
  int tid = threadIdx.x;
  {
    float ang = (float)tid * (6.283185307179586f/256.f);
    ctab[tid] = cosf(ang); stab[tid] = sinf(ang);
  }
  __syncthreads();
  int gid = blockIdx.x*256 + tid;                  // f*16384 + c*128 + k
  int k = gid & 127, c = (gid>>7)&127, f = gid>>14;
  const float* r = cft + (f*128 + c)*256;
  float ar = 0.f, as = 0.f;
  for (int t=0; t<256; ++t){
    float rv = r[t];
    int m = (k*t) & 255;
    ar += rv*ctab[m];
    as += rv*stab[m];
  }
  // hinp = conj((-1)^k H[k] X[k] /256) / mult_pad[k] * mask[k]
  float q;
  if (k == 0) q = 1.f/128.f;                       // H=1, mult_pad=0.5
  else {
    float mk = (fabsf(times[2*k]) > 0.f) ? 1.f : 0.f;
    q = ((k & 1) ? -1.f : 1.f) * (1.f/128.f) * mk; // H=2 /256
  }
  float* o = hinp + (c*256 + 2*k)*16 + f;
  o[0]  = q*ar;                                    // Re
  o[16] = q*as;                                    // Im (= -Im X, conj)
}

// ---------------- hout_cat = [dfh_tanh(skip_h), hinp]; init fnorm bits ------
__global__ __launch_bounds__(256) void k_houtcat(const float* __restrict__ skip,
                                                 const float* __restrict__ hinp,
                                                 float* __restrict__ hc,
                                                 unsigned* __restrict__ fb)
{
  int gid = blockIdx.x*256 + threadIdx.x;          // c*256 + t
  if (gid == 0) *fb = 0u;
  if (gid >= NCC*NTT) return;
  #pragma unroll
  for (int f=0; f<16; ++f){
    hc[gid*32 + f]      = dfh_tanh_f(skip[gid*16+f]);
    hc[gid*32 + 16 + f] = hinp[gid*16+f];
  }
}

// ---------------- stage E DFT: hout_ft[c][t][f] = Re(S[(t+128)&255]) --------
__global__ __launch_bounds__(256) void k_dft_e(const float* __restrict__ hc,
                                               float* __restrict__ hft)
{
  __shared__ float ctab[256], stab[256];
  int tid = threadIdx.x;
  {
    float ang = (float)tid * (6.283185307179586f/256.f);
    ctab[tid] = cosf(ang); stab[tid] = sinf(ang);
  }
  __syncthreads();
  int gid = blockIdx.x*256 + tid;                  // c*8192 + t*32 + f
  int f = gid & 31, t = (gid>>5)&255, c = gid>>13;
  int j = (t + 128) & 255;
  const float* base = hc + c*(256*32) + f;
  float acc = 0.5f*base[0];                        // k=0 (winH 0.5)
  for (int k=1; k<128; ++k){
    float re = base[(2*k)*32], im = base[(2*k+1)*32];
    int m = (j*k) & 255;
    acc += re*ctab[m] + im*stab[m];
  }
  hft[(c*256 + t)*32 + f] = acc;
}

// ---------------- fnorm = max |hft| ------------------------------------------
__global__ __launch_bounds__(256) void k_fnorm(const float* __restrict__ hft,
                                               unsigned* __restrict__ fb, int n)
{
  float m = 0.f;
  for (int i = blockIdx.x*256 + threadIdx.x; i < n; i += gridDim.x*256)
    m = fmaxf(m, fabsf(hft[i]));
  #pragma unroll
  for (int off=32; off>0; off>>=1) m = fmaxf(m, __shfl_down(m, off));
  if ((threadIdx.x & 63) == 0) atomicMax(fb, __float_as_uint(m));
}

// ---------------- ref init: tile(hft/fnorm, 2) ------------------------------
__global__ __launch_bounds__(256) void k_refinit(const float* __restrict__ hft,
                                                 const unsigned* __restrict__ fb,
                                                 float* __restrict__ ref)
{
  int gid = blockIdx.x*256 + threadIdx.x;          // ct*64 + f
  if (gid >= NCC*NTT*64) return;
  float fn = __uint_as_float(*fb);
  int f = gid & 63, ct = gid >> 6;
  ref[gid] = hft[ct*32 + (f & 31)] / fn;
}

// ---------------- refine 9x9 SAME conv (64->32) + act + residual ------------
// src/dst: [c][t][64]; wgt: [kh][kw][ci][o] (9,9,64,32)
__global__ __launch_bounds__(256) void k_refconv(
    const float* __restrict__ src, float* __restrict__ dst,
    const float* __restrict__ wgt, const float* __restrict__ b,
    int choff, int isRelu)
{
  int gid = blockIdx.x*256 + threadIdx.x;          // c*8192 + t*32 + o
  int o = gid & 31, t = (gid>>5)&255, c = gid>>13;
  float acc = b[o];
  for (int kh=0; kh<9; ++kh){
    int cc = c + kh - 4;
    if (cc < 0 || cc >= 128) continue;
    for (int kw=0; kw<9; ++kw){
      int tt = t + kw - 4;
      if (tt < 0 || tt >= 256) continue;
      const float4* sp4 = reinterpret_cast<const float4*>(src + (cc*256 + tt)*64);
      const float* wp = wgt + (kh*9+kw)*(64*32) + o;
      #pragma unroll
      for (int q=0; q<16; ++q){
        float4 s = sp4[q];
        const float* wq = wp + q*128;              // 4 ci * 32
        acc += s.x*wq[0] + s.y*wq[32] + s.z*wq[64] + s.w*wq[96];
      }
    }
  }
  float v = isRelu ? (acc > 0.f ? acc : 0.02f*acc) : dfh_tanh_f(acc);
  int idx = (c*256 + t)*64 + choff + o;
  dst[idx] = v + src[idx];
}

// ---------------- final dense (96 -> 2), fnorm scaling fused ----------------
__global__ __launch_bounds__(256) void k_final(const float* __restrict__ ref,
                                               const float* __restrict__ hft,
                                               const unsigned* __restrict__ fb,
                                               const float* __restrict__ dw,
                                               const float* __restrict__ db,
                                               float* __restrict__ out)
{
  int gid = blockIdx.x*256 + threadIdx.x;          // c*256 + t
  if (gid >= NCC*NTT) return;
  float fn = __uint_as_float(*fb);
  const float* rp = ref + gid*64;
  const float* hp = hft + gid*32;
  float s0 = db[0], s1 = db[1];
  #pragma unroll 8
  for (int f=0; f<64; ++f){ float v = rp[f]*fn; s0 += v*dw[f*2]; s1 += v*dw[f*2+1]; }
  #pragma unroll 8
  for (int f=0; f<32; ++f){ float v = hp[f]; s0 += v*dw[(64+f)*2]; s1 += v*dw[(64+f)*2+1]; }
  out[gid*2]   = s0;
  out[gid*2+1] = s1/fn;
}

extern "C" void kernel_launch(void* const* d_in, const int* in_sizes, int n_in,
                              void* d_out, int out_size, void* d_ws, size_t ws_size,
                              hipStream_t stream)
{
  const float* times    = (const float*)d_in[0];
  const float* times_in = (const float*)d_in[1];
  const float* i2nc     = (const float*)d_in[2];
  const float* i2c      = (const float*)d_in[3];
  const float* cdw  = (const float*)d_in[4];  const float* cdb  = (const float*)d_in[5];
  const float* cwy1 = (const float*)d_in[6];  const float* cby1 = (const float*)d_in[7];
  const float* cwy2 = (const float*)d_in[8];  const float* cby2 = (const float*)d_in[9];
  const float* cwz0 = (const float*)d_in[10]; const float* cbz0 = (const float*)d_in[11];
  const float* hdw  = (const float*)d_in[12]; const float* hdb  = (const float*)d_in[13];
  const float* hwy1 = (const float*)d_in[14]; const float* hby1 = (const float*)d_in[15];
  const float* hwy2 = (const float*)d_in[16]; const float* hby2 = (const float*)d_in[17];
  const float* hwz0 = (const float*)d_in[18]; const float* hbz0 = (const float*)d_in[19];
  const float* rwr  = (const float*)d_in[20]; const float* rbr  = (const float*)d_in[21];
  const float* rwt  = (const float*)d_in[22]; const float* rbt  = (const float*)d_in[23];
  const float* fdw  = (const float*)d_in[24]; const float* fdb  = (const float*)d_in[25];
  float* out = (float*)d_out;

  // ---- workspace layout (floats). refA overlays the dead c-stage region. ---
  float* ws = (float*)d_ws;
  float* x_c   = ws + 0;         // 524288  (later: cft)
  float* skp_c = ws + 524288;    // 524288  (later: x_h)
  float* g     = ws + 1048576;   // 262144  (shared by both fidnet layers)
  float* cout  = ws + 1310720;   // 524288  (later: skp_h)
  float* hinp  = ws + 1835008;   // 524288
  float* cft   = x_c;            // alias (x_c dead after c-layers)
  float* x_h   = skp_c;          // alias (skp_c dead after k_dtanh)
  float* skp_h = cout;           // alias (cout dead after k_dft_c1)
  float* refA  = ws + 0;         // 2097152 overlays [0, 2097152) — dead after k_houtcat
  float* hcat  = ws + 2359296;   // 1048576
  float* hft   = ws + 3407872;   // 1048576
  float* refB  = ws + 4456448;   // 2097152
  unsigned* fb = (unsigned*)(ws + 6553600);
  // total: 6,553,601 floats ~= 26.2 MB

  static const int DILS[15] = {1,2,3,4,6,8,10,12,14,16,18,20,24,28,32};

  // ---- c fidnet layer (H=256 t, W=128 c) ----
  k_build_c<<<128,256,0,stream>>>(times, times_in, i2nc, i2c, cdw, cdb, x_c, skp_c);
  for (int i=0; i<45; ++i){
    int dil = DILS[i % 15];
    k_gate<<<1024,256,0,stream>>>(x_c, g, cwy1 + i*5120, cby1 + i*8,
                                  cwy2 + i*5120, cby2 + i*8, 256, 128, dil);
    k_zres<<<2048,256,0,stream>>>(g, x_c, skp_c, cwz0 + i*5120, cbz0 + i*16, 256, 128);
  }
  k_dtanh<<<2048,256,0,stream>>>(skp_c, cout, 524288);

  // ---- spectral block ----
  k_dft_c1<<<2048,256,0,stream>>>(cout, cft);
  k_dft_c2<<<1024,256,0,stream>>>(cft, times, hinp);

  // ---- h fidnet layer (H=128 c, W=256 t) ----
  k_build_h<<<128,256,0,stream>>>(hinp, hdw, hdb, x_h, skp_h);
  for (int i=0; i<45; ++i){
    int dil = DILS[i % 15];
    k_gate<<<1024,256,0,stream>>>(x_h, g, hwy1 + i*5120, hby1 + i*8,
                                  hwy2 + i*5120, hby2 + i*8, 128, 256, dil);
    k_zres<<<2048,256,0,stream>>>(g, x_h, skp_h, hwz0 + i*5120, hbz0 + i*16, 128, 256);
  }
  k_houtcat<<<128,256,0,stream>>>(skp_h, hinp, hcat, fb);

  // ---- stage E DFT + fnorm ----
  k_dft_e<<<4096,256,0,stream>>>(hcat, hft);
  k_fnorm<<<1024,256,0,stream>>>(hft, fb, 1048576);

  // ---- refine ----
  k_refinit<<<8192,256,0,stream>>>(hft, fb, refA);
  float* rsrc = refA; float* rdst = refB;
  for (int i=0; i<4; ++i){
    k_refconv<<<4096,256,0,stream>>>(rsrc, rdst, rwt + i*165888, rbt + i*32, 0,  0);
    k_refconv<<<4096,256,0,stream>>>(rsrc, rdst, rwr + i*165888, rbr + i*32, 32, 1);
    float* tmp = rsrc; rsrc = rdst; rdst = tmp;
  }

  // ---- final dense ----
  k_final<<<128,256,0,stream>>>(rsrc, hft, fb, fdw, fdb, out);
}

// Round 2
// 8941.876 us; speedup vs baseline: 1.9637x; 1.9637x over previous
//
#include <hip/hip_runtime.h>

#define NTT 256
#define NCC 128

typedef __attribute__((ext_vector_type(8))) short bf16x8;
typedef __attribute__((ext_vector_type(4))) float f32x4;

__device__ __forceinline__ float dfh_tanh_f(float v){ return tanhf(v)*0.98f + 0.02f*v; }
__device__ __forceinline__ float dfh_sig_f(float v){ return 0.98f/(1.f+expf(-v)) + 0.02f*v; }
__device__ __forceinline__ unsigned f2bf(float x){
  unsigned u = __float_as_uint(x);
  return (u + 0x7fffu + ((u>>16)&1u)) >> 16;
}

// ---------------- build c-layer input + dense + tanh; zero skip -------------
__global__ __launch_bounds__(256) void k_build_c(
    const float* __restrict__ times, const float* __restrict__ times_in,
    const float* __restrict__ i2nc, const float* __restrict__ i2c,
    const float* __restrict__ dw, const float* __restrict__ db,
    float* __restrict__ x, float* __restrict__ skip)
{
  int gid = blockIdx.x*256 + threadIdx.x;          // t*128 + c
  if (gid >= NTT*NCC) return;
  int c = gid & 127, t = gid >> 7;
  float v0 = i2nc[c*NTT + t];
  float v1 = i2c [c*NTT + t];
  float v2 = times[t];
  float v3 = times_in[c];
  #pragma unroll
  for (int f=0; f<16; ++f){
    float a = v0*dw[f] + v1*dw[16+f] + v2*dw[32+f] + v3*dw[48+f] + db[f];
    x[gid*16+f]    = dfh_tanh_f(a);
    skip[gid*16+f] = 0.f;
  }
}

// ---------------- h-layer dense + tanh; zero skip ---------------------------
__global__ __launch_bounds__(256) void k_build_h(
    const float* __restrict__ hinp, const float* __restrict__ dw,
    const float* __restrict__ db, float* __restrict__ x, float* __restrict__ skip)
{
  int gid = blockIdx.x*256 + threadIdx.x;          // c*256 + t
  if (gid >= NCC*NTT) return;
  const float* in = hinp + gid*16;
  float iv[16];
  #pragma unroll
  for (int i=0;i<16;i++) iv[i]=in[i];
  #pragma unroll
  for (int f=0; f<16; ++f){
    float a = db[f];
    #pragma unroll
    for (int i=0;i<16;i++) a += iv[i]*dw[i*16+f];
    x[gid*16+f]    = dfh_tanh_f(a);
    skip[gid*16+f] = 0.f;
  }
}

// ---------------- gated dilated conv: g = dfh_tanh(conv1)*dfh_sigmoid(conv2)
__global__ __launch_bounds__(256) void k_gate(
    const float* __restrict__ x, float* __restrict__ g,
    const float* __restrict__ wy1, const float* __restrict__ by1,
    const float* __restrict__ wy2, const float* __restrict__ by2,
    int H, int W, int dil)
{
  int gid = blockIdx.x*256 + threadIdx.x;
  int f  = gid & 7;
  int hw = gid >> 3;
  if (hw >= H*W) return;
  int w = hw % W, h = hw / W;
  float a1 = by1[f], a2 = by2[f];
  for (int kh=0; kh<5; ++kh){
    int hh = h + kh - 2;
    if (hh < 0 || hh >= H) continue;
    const float* xrow = x + hh*W*16;
    for (int kw=0; kw<8; ++kw){
      int ww = w + dil*kw;
      if (ww >= W) break;
      const float4* xp = reinterpret_cast<const float4*>(xrow + ww*16);
      const float* w1 = wy1 + (kh*8+kw)*128 + f;
      const float* w2 = wy2 + (kh*8+kw)*128 + f;
      #pragma unroll
      for (int q=0; q<4; ++q){
        float4 xv = xp[q];
        a1 += xv.x*w1[(q*4+0)*8] + xv.y*w1[(q*4+1)*8] + xv.z*w1[(q*4+2)*8] + xv.w*w1[(q*4+3)*8];
        a2 += xv.x*w2[(q*4+0)*8] + xv.y*w2[(q*4+1)*8] + xv.z*w2[(q*4+2)*8] + xv.w*w2[(q*4+3)*8];
      }
    }
  }
  g[hw*8+f] = dfh_tanh_f(a1)*dfh_sig_f(a2);
}

// ---------------- z-conv (dil=1) + residual updates: skip+=z, x+=z ----------
__global__ __launch_bounds__(256) void k_zres(
    const float* __restrict__ g, float* __restrict__ x, float* __restrict__ skip,
    const float* __restrict__ wz, const float* __restrict__ bz, int H, int W)
{
  int gid = blockIdx.x*256 + threadIdx.x;
  int fo = gid & 15;
  int hw = gid >> 4;
  if (hw >= H*W) return;
  int w = hw % W, h = hw / W;
  float acc = bz[fo];
  for (int kh=0; kh<5; ++kh){
    int hh = h + kh - 2;
    if (hh < 0 || hh >= H) continue;
    const float* grow = g + hh*W*8;
    for (int kw=0; kw<8; ++kw){
      int ww = w + kw;
      if (ww >= W) break;
      const float4* gp = reinterpret_cast<const float4*>(grow + ww*8);
      const float* wp = wz + (kh*8+kw)*128 + fo;
      float4 g0 = gp[0], g1 = gp[1];
      acc += g0.x*wp[0]   + g0.y*wp[16]  + g0.z*wp[32]  + g0.w*wp[48]
           + g1.x*wp[64]  + g1.y*wp[80]  + g1.z*wp[96]  + g1.w*wp[112];
    }
  }
  int idx = hw*16 + fo;
  skip[idx] += acc;
  x[idx]    += acc;
}

// ---------------- cout = dfh_tanh(skip) -------------------------------------
__global__ __launch_bounds__(256) void k_dtanh(const float* __restrict__ s,
                                               float* __restrict__ o, int n)
{
  int i = blockIdx.x*256 + threadIdx.x;
  if (i < n) o[i] = dfh_tanh_f(s[i]);
}

// ---------------- stage C, DFT #1 -------------------------------------------
__global__ __launch_bounds__(256) void k_dft_c1(const float* __restrict__ cout,
                                                float* __restrict__ cft)
{
  __shared__ float ctab[128], stab[128];
  int tid = threadIdx.x;
  if (tid < 128){
    float ang = (float)tid * (6.283185307179586f/128.f);
    ctab[tid] = cosf(ang); stab[tid] = sinf(ang);
  }
  __syncthreads();
  int gid = blockIdx.x*256 + tid;                  // f*32768 + c*256 + t
  int t = gid & 255, c = (gid>>8)&127, f = gid>>15;
  int j = (c + 64) & 127;
  const float* base = cout + t*(128*16) + f;
  float acc = 0.5f*base[0];
  for (int k=1; k<64; ++k){
    float re = base[(2*k)*16], im = base[(2*k+1)*16];
    int m = (j*k) & 127;
    acc += re*ctab[m] + im*stab[m];
  }
  cft[(f*128 + c)*256 + t] = acc;
}

// ---------------- stage C, DFT #2 + hilbert/conj/mask collapse --------------
__global__ __launch_bounds__(256) void k_dft_c2(const float* __restrict__ cft,
                                                const float* __restrict__ times,
                                                float* __restrict__ hinp)
{
  __shared__ float ctab[256], stab[256];
  int tid = threadIdx.x;
  {
    float ang = (float)tid * (6.283185307179586f/256.f);
    ctab[tid] = cosf(ang); stab[tid] = sinf(ang);
  }
  __syncthreads();
  int gid = blockIdx.x*256 + tid;                  // f*16384 + c*128 + k
  int k = gid & 127, c = (gid>>7)&127, f = gid>>14;
  const float* r = cft + (f*128 + c)*256;
  float ar = 0.f, as = 0.f;
  for (int t=0; t<256; ++t){
    float rv = r[t];
    int m = (k*t) & 255;
    ar += rv*ctab[m];
    as += rv*stab[m];
  }
  float q;
  if (k == 0) q = 1.f/128.f;
  else {
    float mk = (fabsf(times[2*k]) > 0.f) ? 1.f : 0.f;
    q = ((k & 1) ? -1.f : 1.f) * (1.f/128.f) * mk;
  }
  float* o = hinp + (c*256 + 2*k)*16 + f;
  o[0]  = q*ar;
  o[16] = q*as;
}

// ---------------- hout_cat = [dfh_tanh(skip_h), hinp]; init fnorm bits ------
__global__ __launch_bounds__(256) void k_houtcat(const float* __restrict__ skip,
                                                 const float* __restrict__ hinp,
                                                 float* __restrict__ hc,
                                                 unsigned* __restrict__ fb)
{
  int gid = blockIdx.x*256 + threadIdx.x;          // c*256 + t
  if (gid == 0) *fb = 0u;
  if (gid >= NCC*NTT) return;
  #pragma unroll
  for (int f=0; f<16; ++f){
    hc[gid*32 + f]      = dfh_tanh_f(skip[gid*16+f]);
    hc[gid*32 + 16 + f] = hinp[gid*16+f];
  }
}

// ---------------- stage E DFT ------------------------------------------------
__global__ __launch_bounds__(256) void k_dft_e(const float* __restrict__ hc,
                                               float* __restrict__ hft)
{
  __shared__ float ctab[256], stab[256];
  int tid = threadIdx.x;
  {
    float ang = (float)tid * (6.283185307179586f/256.f);
    ctab[tid] = cosf(ang); stab[tid] = sinf(ang);
  }
  __syncthreads();
  int gid = blockIdx.x*256 + tid;                  // c*8192 + t*32 + f
  int f = gid & 31, t = (gid>>5)&255, c = gid>>13;
  int j = (t + 128) & 255;
  const float* base = hc + c*(256*32) + f;
  float acc = 0.5f*base[0];
  for (int k=1; k<128; ++k){
    float re = base[(2*k)*32], im = base[(2*k+1)*32];
    int m = (j*k) & 255;
    acc += re*ctab[m] + im*stab[m];
  }
  hft[(c*256 + t)*32 + f] = acc;
}

// ---------------- fnorm = max |hft| ------------------------------------------
__global__ __launch_bounds__(256) void k_fnorm(const float* __restrict__ hft,
                                               unsigned* __restrict__ fb, int n)
{
  float m = 0.f;
  for (int i = blockIdx.x*256 + threadIdx.x; i < n; i += gridDim.x*256)
    m = fmaxf(m, fabsf(hft[i]));
  #pragma unroll
  for (int off=32; off>0; off>>=1) m = fmaxf(m, __shfl_down(m, off));
  if ((threadIdx.x & 63) == 0) atomicMax(fb, __float_as_uint(m));
}

// ---------------- ref init: tile(hft/fnorm, 2) ------------------------------
__global__ __launch_bounds__(256) void k_refinit(const float* __restrict__ hft,
                                                 const unsigned* __restrict__ fb,
                                                 float* __restrict__ ref)
{
  int gid = blockIdx.x*256 + threadIdx.x;          // ct*64 + f
  if (gid >= NCC*NTT*64) return;
  float fn = __uint_as_float(*fb);
  int f = gid & 63, ct = gid >> 6;
  ref[gid] = hft[ct*32 + (f & 31)] / fn;
}

// ---------------- refine weights -> bf16 MFMA fragment order ----------------
// Bfrag[frag=(p*2+kt)*4... actually frag = p*8 + kt*4 + nt][lane][8 bf16]
// value = W[p][ci = kt*32+(lane>>4)*8+j][o = nt*16+(lane&15)], o<32 from wt else wr
__global__ __launch_bounds__(256) void k_wconv(
    const float* __restrict__ wt, const float* __restrict__ wr,
    unsigned short* __restrict__ bfrag)
{
  int gid = blockIdx.x*256 + threadIdx.x;  // frag*64 + lane
  if (gid >= 648*64) return;
  int lane = gid & 63, frag = gid >> 6;
  int nt = frag & 3, kt = (frag>>2) & 1, p = frag >> 3;
  int o = nt*16 + (lane & 15);
  int ci0 = kt*32 + (lane>>4)*8;
  const float* src = (o < 32) ? (wt + (p*64 + ci0)*32 + o)
                              : (wr + (p*64 + ci0)*32 + (o-32));
  unsigned pk[4];
  #pragma unroll
  for (int j=0;j<4;++j)
    pk[j] = f2bf(src[(2*j)*32]) | (f2bf(src[(2*j+1)*32]) << 16);
  uint4 v; v.x = pk[0]; v.y = pk[1]; v.z = pk[2]; v.w = pk[3];
  *reinterpret_cast<uint4*>(bfrag + (size_t)gid*8) = v;
}

// ---------------- refine: fused tt/rr 9x9 conv via MFMA ---------------------
// src: [c][t][64] f32 (residual + on-the-fly bf16 staging), dst: same layout.
// bfrag: per-step weight fragments. 256 blocks (c*2 + thalf), 512 threads.
__global__ __launch_bounds__(512) void k_refmfma(
    const float* __restrict__ srcf, float* __restrict__ dstf,
    const unsigned short* __restrict__ bfrag,
    const float* __restrict__ bt, const float* __restrict__ br)
{
  __shared__ __align__(16) unsigned short ldsA[136*64];   // 17408 B, XOR-swizzled
  const int tid  = threadIdx.x;
  const int lane = tid & 63;
  const int wv   = tid >> 6;
  const int c    = blockIdx.x >> 1;
  const int t0   = (blockIdx.x & 1) * 128;

  f32x4 acc[4];
  #pragma unroll
  for (int nt=0; nt<4; ++nt) acc[nt] = (f32x4){0.f,0.f,0.f,0.f};

  for (int kh=0; kh<9; ++kh){
    int cc = c + kh - 4;
    if (cc < 0 || cc >= 128) continue;      // uniform per block
    // ---- stage A row (136 t-rows x 64 ci) f32 -> bf16, swizzled ----
    for (int q = tid; q < 1088; q += 512){
      int row = q >> 3, c16 = q & 7;
      int t = t0 - 4 + row;
      uint4 v = make_uint4(0u,0u,0u,0u);
      if (t >= 0 && t < 256){
        const float* sp = srcf + ((size_t)(cc*256 + t))*64 + c16*8;
        float4 f0 = *reinterpret_cast<const float4*>(sp);
        float4 f1 = *reinterpret_cast<const float4*>(sp + 4);
        v.x = f2bf(f0.x) | (f2bf(f0.y)<<16);
        v.y = f2bf(f0.z) | (f2bf(f0.w)<<16);
        v.z = f2bf(f1.x) | (f2bf(f1.y)<<16);
        v.w = f2bf(f1.z) | (f2bf(f1.w)<<16);
      }
      *reinterpret_cast<uint4*>(&ldsA[row*64 + ((c16 ^ (row&7))*8)]) = v;
    }
    __syncthreads();
    for (int kw=0; kw<9; ++kw){
      const int p = kh*9 + kw;
      const unsigned short* bb = bfrag + (size_t)p*8*64*8;
      bf16x8 b[2][4];
      #pragma unroll
      for (int kt=0; kt<2; ++kt)
        #pragma unroll
        for (int nt=0; nt<4; ++nt)
          b[kt][nt] = *reinterpret_cast<const bf16x8*>(bb + ((kt*4+nt)*64 + lane)*8);
      const int j = wv*16 + (lane&15) + kw;   // LDS row (t = t0-4+j)
      #pragma unroll
      for (int kt=0; kt<2; ++kt){
        bf16x8 a = *reinterpret_cast<const bf16x8*>(
            &ldsA[j*64 + (((kt*4 + (lane>>4)) ^ (j&7))*8)]);
        #pragma unroll
        for (int nt=0; nt<4; ++nt)
          acc[nt] = __builtin_amdgcn_mfma_f32_16x16x32_bf16(a, b[kt][nt], acc[nt], 0,0,0);
      }
    }
    __syncthreads();
  }

  // ---- epilogue: bias + act + residual, f32 store ----
  const int mbase = wv*16 + (lane>>4)*4;
  #pragma unroll
  for (int nt=0; nt<4; ++nt){
    int o = nt*16 + (lane&15);
    float bv = (o < 32) ? bt[o] : br[o-32];
    #pragma unroll
    for (int ri=0; ri<4; ++ri){
      int t = t0 + mbase + ri;
      float v = acc[nt][ri] + bv;
      v = (nt < 2) ? dfh_tanh_f(v) : (v > 0.f ? v : 0.02f*v);
      size_t idx = ((size_t)(c*256 + t))*64 + o;
      dstf[idx] = v + srcf[idx];
    }
  }
}

// ---------------- final dense (96 -> 2), fnorm scaling fused ----------------
__global__ __launch_bounds__(256) void k_final(const float* __restrict__ ref,
                                               const float* __restrict__ hft,
                                               const unsigned* __restrict__ fb,
                                               const float* __restrict__ dw,
                                               const float* __restrict__ db,
                                               float* __restrict__ out)
{
  int gid = blockIdx.x*256 + threadIdx.x;          // c*256 + t
  if (gid >= NCC*NTT) return;
  float fn = __uint_as_float(*fb);
  const float* rp = ref + gid*64;
  const float* hp = hft + gid*32;
  float s0 = db[0], s1 = db[1];
  #pragma unroll 8
  for (int f=0; f<64; ++f){ float v = rp[f]*fn; s0 += v*dw[f*2]; s1 += v*dw[f*2+1]; }
  #pragma unroll 8
  for (int f=0; f<32; ++f){ float v = hp[f]; s0 += v*dw[(64+f)*2]; s1 += v*dw[(64+f)*2+1]; }
  out[gid*2]   = s0;
  out[gid*2+1] = s1/fn;
}

extern "C" void kernel_launch(void* const* d_in, const int* in_sizes, int n_in,
                              void* d_out, int out_size, void* d_ws, size_t ws_size,
                              hipStream_t stream)
{
  const float* times    = (const float*)d_in[0];
  const float* times_in = (const float*)d_in[1];
  const float* i2nc     = (const float*)d_in[2];
  const float* i2c      = (const float*)d_in[3];
  const float* cdw  = (const float*)d_in[4];  const float* cdb  = (const float*)d_in[5];
  const float* cwy1 = (const float*)d_in[6];  const float* cby1 = (const float*)d_in[7];
  const float* cwy2 = (const float*)d_in[8];  const float* cby2 = (const float*)d_in[9];
  const float* cwz0 = (const float*)d_in[10]; const float* cbz0 = (const float*)d_in[11];
  const float* hdw  = (const float*)d_in[12]; const float* hdb  = (const float*)d_in[13];
  const float* hwy1 = (const float*)d_in[14]; const float* hby1 = (const float*)d_in[15];
  const float* hwy2 = (const float*)d_in[16]; const float* hby2 = (const float*)d_in[17];
  const float* hwz0 = (const float*)d_in[18]; const float* hbz0 = (const float*)d_in[19];
  const float* rwr  = (const float*)d_in[20]; const float* rbr  = (const float*)d_in[21];
  const float* rwt  = (const float*)d_in[22]; const float* rbt  = (const float*)d_in[23];
  const float* fdw  = (const float*)d_in[24]; const float* fdb  = (const float*)d_in[25];
  float* out = (float*)d_out;

  // ---- workspace layout (floats), aliased by liveness ----------------------
  float* ws = (float*)d_ws;
  float* x_c   = ws + 0;         // 524288
  float* skp_c = ws + 524288;    // 524288
  float* g     = ws + 1048576;   // 262144
  float* cout  = ws + 1310720;   // 524288
  float* hinp  = ws + 1835008;   // 524288
  float* cft   = x_c;            // alias (x_c dead after c-layers)
  float* x_h   = skp_c;          // alias
  float* skp_h = cout;           // alias
  float* refA  = ws + 0;         // 2097152, overlays dead c-stage + hinp head
  unsigned short* bfragS = (unsigned short*)(ws + 2097152); // 165888 bf16 (hinp tail, dead post-houtcat)
  float* hcat  = ws + 2359296;   // 1048576
  float* hft   = ws + 3407872;   // 1048576
  float* refB  = ws + 4456448;   // 2097152
  unsigned* fb = (unsigned*)(ws + 6553600);
  // total: 6,553,601 floats ~= 26.2 MB

  static const int DILS[15] = {1,2,3,4,6,8,10,12,14,16,18,20,24,28,32};

  // ---- c fidnet layer (H=256 t, W=128 c) ----
  k_build_c<<<128,256,0,stream>>>(times, times_in, i2nc, i2c, cdw, cdb, x_c, skp_c);
  for (int i=0; i<45; ++i){
    int dil = DILS[i % 15];
    k_gate<<<1024,256,0,stream>>>(x_c, g, cwy1 + i*5120, cby1 + i*8,
                                  cwy2 + i*5120, cby2 + i*8, 256, 128, dil);
    k_zres<<<2048,256,0,stream>>>(g, x_c, skp_c, cwz0 + i*5120, cbz0 + i*16, 256, 128);
  }
  k_dtanh<<<2048,256,0,stream>>>(skp_c, cout, 524288);

  // ---- spectral block ----
  k_dft_c1<<<2048,256,0,stream>>>(cout, cft);
  k_dft_c2<<<1024,256,0,stream>>>(cft, times, hinp);

  // ---- h fidnet layer (H=128 c, W=256 t) ----
  k_build_h<<<128,256,0,stream>>>(hinp, hdw, hdb, x_h, skp_h);
  for (int i=0; i<45; ++i){
    int dil = DILS[i % 15];
    k_gate<<<1024,256,0,stream>>>(x_h, g, hwy1 + i*5120, hby1 + i*8,
                                  hwy2 + i*5120, hby2 + i*8, 128, 256, dil);
    k_zres<<<2048,256,0,stream>>>(g, x_h, skp_h, hwz0 + i*5120, hbz0 + i*16, 128, 256);
  }
  k_houtcat<<<128,256,0,stream>>>(skp_h, hinp, hcat, fb);

  // ---- stage E DFT + fnorm ----
  k_dft_e<<<4096,256,0,stream>>>(hcat, hft);
  k_fnorm<<<1024,256,0,stream>>>(hft, fb, 1048576);

  // ---- refine: 4 steps, fused tt/rr MFMA conv ----
  k_refinit<<<8192,256,0,stream>>>(hft, fb, refA);
  float* rsrc = refA; float* rdst = refB;
  for (int i=0; i<4; ++i){
    k_wconv<<<162,256,0,stream>>>(rwt + i*165888, rwr + i*165888, bfragS);
    k_refmfma<<<256,512,0,stream>>>(rsrc, rdst, bfragS, rbt + i*32, rbr + i*32);
    float* tmp = rsrc; rsrc = rdst; rdst = tmp;
  }

  // ---- final dense ----
  k_final<<<128,256,0,stream>>>(rsrc, hft, fb, fdw, fdb, out);
}

// Round 7
// 1774.806 us; speedup vs baseline: 9.8937x; 5.0382x over previous
//
#include <hip/hip_runtime.h>

#define NTT 256
#define NCC 128

typedef __attribute__((ext_vector_type(8))) short bf16x8;
typedef __attribute__((ext_vector_type(4))) float f32x4;

__device__ __forceinline__ float dfh_tanh_f(float v){ return tanhf(v)*0.98f + 0.02f*v; }
__device__ __forceinline__ float dfh_sig_f(float v){ return 0.98f/(1.f+expf(-v)) + 0.02f*v; }
__device__ __forceinline__ unsigned f2bf(float x){
  unsigned u = __float_as_uint(x);
  return (u + 0x7fffu + ((u>>16)&1u)) >> 16;
}

// ---------------- build c-layer input + dense + tanh; zero skip -------------
__global__ __launch_bounds__(256) void k_build_c(
    const float* __restrict__ times, const float* __restrict__ times_in,
    const float* __restrict__ i2nc, const float* __restrict__ i2c,
    const float* __restrict__ dw, const float* __restrict__ db,
    float* __restrict__ x, unsigned short* __restrict__ xb,
    float* __restrict__ skip)
{
  int gid = blockIdx.x*256 + threadIdx.x;          // t*128 + c
  if (gid >= NTT*NCC) return;
  int c = gid & 127, t = gid >> 7;
  float v0 = i2nc[c*NTT + t];
  float v1 = i2c [c*NTT + t];
  float v2 = times[t];
  float v3 = times_in[c];
  #pragma unroll
  for (int f=0; f<16; ++f){
    float a = v0*dw[f] + v1*dw[16+f] + v2*dw[32+f] + v3*dw[48+f] + db[f];
    float xv = dfh_tanh_f(a);
    x[gid*16+f]    = xv;
    xb[gid*16+f]   = (unsigned short)f2bf(xv);
    skip[gid*16+f] = 0.f;
  }
}

// ---------------- h-layer dense + tanh; zero skip ---------------------------
__global__ __launch_bounds__(256) void k_build_h(
    const float* __restrict__ hinp, const float* __restrict__ dw,
    const float* __restrict__ db, float* __restrict__ x,
    unsigned short* __restrict__ xb, float* __restrict__ skip)
{
  int gid = blockIdx.x*256 + threadIdx.x;          // c*256 + t
  if (gid >= NCC*NTT) return;
  const float* in = hinp + gid*16;
  float iv[16];
  #pragma unroll
  for (int i=0;i<16;i++) iv[i]=in[i];
  #pragma unroll
  for (int f=0; f<16; ++f){
    float a = db[f];
    #pragma unroll
    for (int i=0;i<16;i++) a += iv[i]*dw[i*16+f];
    float xv = dfh_tanh_f(a);
    x[gid*16+f]    = xv;
    xb[gid*16+f]   = (unsigned short)f2bf(xv);
    skip[gid*16+f] = 0.f;
  }
}

// ---------------- pack wave-layer weights into MFMA fragment order ----------
// gate frags: [90 layers][20 ksteps][64 lanes][8]: B[k][n], k=640 (40 taps x16ci),
//   n<8 -> wy1 f=n, n>=8 -> wy2 f=n-8.  k = ks*32 + (lane>>4)*8 + j.
// zres frags: [90][10][64][8]: K=320 (40 taps x 8ci), n=fo.
__global__ __launch_bounds__(256) void k_wpack(
    const float* __restrict__ cwy1, const float* __restrict__ cwy2,
    const float* __restrict__ cwz0,
    const float* __restrict__ hwy1, const float* __restrict__ hwy2,
    const float* __restrict__ hwz0,
    unsigned short* __restrict__ gfrag, unsigned short* __restrict__ zfrag)
{
  int tid = blockIdx.x*256 + threadIdx.x;
  if (tid < 115200){
    int lane = tid & 63, ks = (tid>>6) % 20, layer = tid / 1280;
    const float* w1 = (layer < 45) ? cwy1 + layer*5120 : hwy1 + (layer-45)*5120;
    const float* w2 = (layer < 45) ? cwy2 + layer*5120 : hwy2 + (layer-45)*5120;
    int n = lane & 15;
    unsigned pk[4];
    #pragma unroll
    for (int jj=0; jj<4; ++jj){
      unsigned hl[2];
      #pragma unroll
      for (int h2=0; h2<2; ++h2){
        int k = ks*32 + (lane>>4)*8 + jj*2 + h2;
        int tap = k>>4, ci = k&15;
        float v = (n<8) ? w1[(tap*16+ci)*8 + n] : w2[(tap*16+ci)*8 + (n-8)];
        hl[h2] = f2bf(v);
      }
      pk[jj] = hl[0] | (hl[1]<<16);
    }
    uint4 v4; v4.x=pk[0]; v4.y=pk[1]; v4.z=pk[2]; v4.w=pk[3];
    *reinterpret_cast<uint4*>(gfrag + (size_t)tid*8) = v4;
  } else if (tid < 172800){
    int t2 = tid - 115200;
    int lane = t2 & 63, ks = (t2>>6) % 10, layer = t2 / 640;
    const float* wz = (layer < 45) ? cwz0 + layer*5120 : hwz0 + (layer-45)*5120;
    int n = lane & 15;
    unsigned pk[4];
    #pragma unroll
    for (int jj=0; jj<4; ++jj){
      unsigned hl[2];
      #pragma unroll
      for (int h2=0; h2<2; ++h2){
        int k = ks*32 + (lane>>4)*8 + jj*2 + h2;
        int tap = k>>3, ci = k&7;
        hl[h2] = f2bf(wz[(tap*8+ci)*16 + n]);
      }
      pk[jj] = hl[0] | (hl[1]<<16);
    }
    uint4 v4; v4.x=pk[0]; v4.y=pk[1]; v4.z=pk[2]; v4.w=pk[3];
    *reinterpret_cast<uint4*>(zfrag + (size_t)t2*8) = v4;
  }
}

// ---------------- gate: g = dfh_tanh(y1)*dfh_sigmoid(y2) via MFMA -----------
// xb: [H][W][16] bf16. grid = H*(W/128), 512 threads. M=128 per block, N=16.
// LDS A layout: entry(row,chunk,col) = (row*2+chunk)*W + col, 16B each.
template<int W>
__global__ __launch_bounds__(512) void k_gate_mfma(
    const unsigned short* __restrict__ xb, unsigned short* __restrict__ gb,
    const unsigned short* __restrict__ bfrag,
    const float* __restrict__ by1, const float* __restrict__ by2,
    int H, int dil)
{
  __shared__ __align__(16) unsigned short lds[(10*W+1)*8];
  const int tid = threadIdx.x, lane = tid & 63, wv = tid >> 6;
  const int nb = W/128;
  const int h  = blockIdx.x / nb;
  const int w0 = (blockIdx.x % nb) * 128;
  const int NE = 10*W;
  for (int q = tid; q < NE; q += 512){
    int q2 = q >> 1, chunk = q & 1;
    int col = q2 % W, r = q2 / W;
    int hh = h + r - 2;
    uint4 v = make_uint4(0u,0u,0u,0u);
    if (hh >= 0 && hh < H)
      v = *reinterpret_cast<const uint4*>(xb + ((size_t)(hh*W+col))*16 + chunk*8);
    *reinterpret_cast<uint4*>(lds + ((r*2+chunk)*W + col)*8) = v;
  }
  if (tid == 0) *reinterpret_cast<uint4*>(lds + (size_t)NE*8) = make_uint4(0u,0u,0u,0u);
  __syncthreads();

  f32x4 acc = (f32x4){0.f,0.f,0.f,0.f};
  const int wbase = w0 + wv*16;
  const int zoff = NE*8;
  for (int ks = 0; ks < 20; ++ks){
    int kh = ks >> 2, kw0 = (ks & 3)*2;
    if (w0 + dil*kw0 >= W) continue;               // uniform: all-zero step
    bf16x8 b = *reinterpret_cast<const bf16x8*>(bfrag + (ks*64 + lane)*8);
    int kw = kw0 + (lane>>5);
    int chunk = (lane>>4) & 1;
    int col = wbase + (lane&15) + dil*kw;
    int off = (col < W) ? ((kh*2+chunk)*W + col)*8 : zoff;
    bf16x8 a = *reinterpret_cast<const bf16x8*>(lds + off);
    acc = __builtin_amdgcn_mfma_f32_16x16x32_bf16(a, b, acc, 0,0,0);
  }

  int n = lane & 15;
  float b1 = by1[n & 7], b2 = by2[n & 7];
  #pragma unroll
  for (int ri=0; ri<4; ++ri){
    float own = acc[ri] + b1;
    float oth = __shfl_xor(acc[ri], 8) + b2;
    if (n < 8){
      float gv = dfh_tanh_f(own) * dfh_sig_f(oth);
      int w = wbase + (lane>>4)*4 + ri;
      gb[((size_t)(h*W + w))*8 + n] = (unsigned short)f2bf(gv);
    }
  }
}

// ---------------- zres: z-conv via MFMA + skip/x residual + bf16 mirror -----
template<int W>
__global__ __launch_bounds__(512) void k_zres_mfma(
    const unsigned short* __restrict__ gb,
    float* __restrict__ x, unsigned short* __restrict__ xb,
    float* __restrict__ skip,
    const unsigned short* __restrict__ bfrag,
    const float* __restrict__ bz, int H)
{
  __shared__ __align__(16) unsigned short lds[(5*W+1)*8];
  const int tid = threadIdx.x, lane = tid & 63, wv = tid >> 6;
  const int nb = W/128;
  const int h  = blockIdx.x / nb;
  const int w0 = (blockIdx.x % nb) * 128;
  for (int q = tid; q < 5*W; q += 512){
    int col = q % W, r = q / W;
    int hh = h + r - 2;
    uint4 v = make_uint4(0u,0u,0u,0u);
    if (hh >= 0 && hh < H)
      v = *reinterpret_cast<const uint4*>(gb + ((size_t)(hh*W+col))*8);
    *reinterpret_cast<uint4*>(lds + (r*W+col)*8) = v;
  }
  if (tid == 0) *reinterpret_cast<uint4*>(lds + (size_t)(5*W)*8) = make_uint4(0u,0u,0u,0u);
  __syncthreads();

  f32x4 acc = (f32x4){0.f,0.f,0.f,0.f};
  const int wbase = w0 + wv*16;
  const int zoff = 5*W*8;
  for (int ks = 0; ks < 10; ++ks){
    int kh = ks >> 1, kw = (ks & 1)*4 + (lane>>4);
    bf16x8 b = *reinterpret_cast<const bf16x8*>(bfrag + (ks*64 + lane)*8);
    int col = wbase + (lane&15) + kw;
    int off = (col < W) ? (kh*W + col)*8 : zoff;
    bf16x8 a = *reinterpret_cast<const bf16x8*>(lds + off);
    acc = __builtin_amdgcn_mfma_f32_16x16x32_bf16(a, b, acc, 0,0,0);
  }

  int n = lane & 15;
  float bv = bz[n];
  #pragma unroll
  for (int ri=0; ri<4; ++ri){
    int w = wbase + (lane>>4)*4 + ri;
    size_t idx = ((size_t)(h*W + w))*16 + n;
    float z = acc[ri] + bv;
    skip[idx] += z;
    float xn = x[idx] + z;
    x[idx]  = xn;
    xb[idx] = (unsigned short)f2bf(xn);
  }
}

// ---------------- cout = dfh_tanh(skip), transposed to [f][ch][t] -----------
__global__ __launch_bounds__(256) void k_dtanh_t(const float* __restrict__ s,
                                                 float* __restrict__ o)
{
  __shared__ float tile[256][17];
  int c = blockIdx.x;                              // 128 blocks
  int tid = threadIdx.x;
  int f = tid & 15, tq = tid >> 4;
  #pragma unroll
  for (int p = 0; p < 16; ++p){
    int t = p*16 + tq;
    tile[t][f] = s[((size_t)t*128 + c)*16 + f];
  }
  __syncthreads();
  int t = tid;
  #pragma unroll
  for (int f2 = 0; f2 < 16; ++f2)
    o[(size_t)f2*32768 + c*256 + t] = dfh_tanh_f(tile[t][f2]);
}

// ---------------- stage C, DFT #1: coalesced over t -------------------------
// cout: [f][ch][t]  ->  cft[f][c][t]
__global__ __launch_bounds__(256) void k_dft_c1(const float* __restrict__ cout,
                                                float* __restrict__ cft)
{
  __shared__ float ctab[128], stab[128];
  int tid = threadIdx.x;
  if (tid < 128){
    float ang = (float)tid * (6.283185307179586f/128.f);
    ctab[tid] = cosf(ang); stab[tid] = sinf(ang);
  }
  __syncthreads();
  int gid = blockIdx.x*256 + tid;                  // f*32768 + c*256 + t
  int t = gid & 255, c = (gid>>8)&127, f = gid>>15;
  int j = (c + 64) & 127;
  const float* base = cout + (size_t)f*32768 + t;
  float acc = 0.5f*base[0];
  for (int k=1; k<64; ++k){
    float re = base[(2*k)*256], im = base[(2*k+1)*256];
    int m = (j*k) & 127;
    acc += re*ctab[m] + im*stab[m];
  }
  cft[(f*128 + c)*256 + t] = acc;
}

// ---------------- stage C, DFT #2 + hilbert/conj/mask collapse --------------
__global__ __launch_bounds__(256) void k_dft_c2(const float* __restrict__ cft,
                                                const float* __restrict__ times,
                                                float* __restrict__ hinp)
{
  __shared__ float ctab[256], stab[256];
  int tid = threadIdx.x;
  {
    float ang = (float)tid * (6.283185307179586f/256.f);
    ctab[tid] = cosf(ang); stab[tid] = sinf(ang);
  }
  __syncthreads();
  int gid = blockIdx.x*256 + tid;                  // f*16384 + c*128 + k
  int k = gid & 127, c = (gid>>7)&127, f = gid>>14;
  const float* r = cft + (f*128 + c)*256;
  float ar = 0.f, as = 0.f;
  for (int t=0; t<256; ++t){
    float rv = r[t];
    int m = (k*t) & 255;
    ar += rv*ctab[m];
    as += rv*stab[m];
  }
  float q;
  if (k == 0) q = 1.f/128.f;
  else {
    float mk = (fabsf(times[2*k]) > 0.f) ? 1.f : 0.f;
    q = ((k & 1) ? -1.f : 1.f) * (1.f/128.f) * mk;
  }
  float* o = hinp + (c*256 + 2*k)*16 + f;
  o[0]  = q*ar;
  o[16] = q*as;
}

// ---------------- hout_cat = [dfh_tanh(skip_h), hinp]; init fnorm bits ------
__global__ __launch_bounds__(256) void k_houtcat(const float* __restrict__ skip,
                                                 const float* __restrict__ hinp,
                                                 float* __restrict__ hc,
                                                 unsigned* __restrict__ fb)
{
  int gid = blockIdx.x*256 + threadIdx.x;          // c*256 + t
  if (gid == 0) *fb = 0u;
  if (gid >= NCC*NTT) return;
  #pragma unroll
  for (int f=0; f<16; ++f){
    hc[gid*32 + f]      = dfh_tanh_f(skip[gid*16+f]);
    hc[gid*32 + 16 + f] = hinp[gid*16+f];
  }
}

// ---------------- stage E DFT ------------------------------------------------
__global__ __launch_bounds__(256) void k_dft_e(const float* __restrict__ hc,
                                               float* __restrict__ hft)
{
  __shared__ float ctab[256], stab[256];
  int tid = threadIdx.x;
  {
    float ang = (float)tid * (6.283185307179586f/256.f);
    ctab[tid] = cosf(ang); stab[tid] = sinf(ang);
  }
  __syncthreads();
  int gid = blockIdx.x*256 + tid;                  // c*8192 + t*32 + f
  int f = gid & 31, t = (gid>>5)&255, c = gid>>13;
  int j = (t + 128) & 255;
  const float* base = hc + c*(256*32) + f;
  float acc = 0.5f*base[0];
  for (int k=1; k<128; ++k){
    float re = base[(2*k)*32], im = base[(2*k+1)*32];
    int m = (j*k) & 255;
    acc += re*ctab[m] + im*stab[m];
  }
  hft[(c*256 + t)*32 + f] = acc;
}

// ---------------- fnorm = max |hft| ------------------------------------------
__global__ __launch_bounds__(256) void k_fnorm(const float* __restrict__ hft,
                                               unsigned* __restrict__ fb, int n)
{
  float m = 0.f;
  for (int i = blockIdx.x*256 + threadIdx.x; i < n; i += gridDim.x*256)
    m = fmaxf(m, fabsf(hft[i]));
  #pragma unroll
  for (int off=32; off>0; off>>=1) m = fmaxf(m, __shfl_down(m, off));
  if ((threadIdx.x & 63) == 0) atomicMax(fb, __float_as_uint(m));
}

// ---------------- ref init: tile(hft/fnorm, 2) ------------------------------
__global__ __launch_bounds__(256) void k_refinit(const float* __restrict__ hft,
                                                 const unsigned* __restrict__ fb,
                                                 float* __restrict__ ref)
{
  int gid = blockIdx.x*256 + threadIdx.x;          // ct*64 + f
  if (gid >= NCC*NTT*64) return;
  float fn = __uint_as_float(*fb);
  int f = gid & 63, ct = gid >> 6;
  ref[gid] = hft[ct*32 + (f & 31)] / fn;
}

// ---------------- refine weights -> bf16 MFMA fragment order ----------------
__global__ __launch_bounds__(256) void k_wconv(
    const float* __restrict__ wt, const float* __restrict__ wr,
    unsigned short* __restrict__ bfrag)
{
  int gid = blockIdx.x*256 + threadIdx.x;  // frag*64 + lane
  if (gid >= 648*64) return;
  int lane = gid & 63, frag = gid >> 6;
  int nt = frag & 3, kt = (frag>>2) & 1, p = frag >> 3;
  int o = nt*16 + (lane & 15);
  int ci0 = kt*32 + (lane>>4)*8;
  const float* src = (o < 32) ? (wt + (p*64 + ci0)*32 + o)
                              : (wr + (p*64 + ci0)*32 + (o-32));
  unsigned pk[4];
  #pragma unroll
  for (int j=0;j<4;++j)
    pk[j] = f2bf(src[(2*j)*32]) | (f2bf(src[(2*j+1)*32]) << 16);
  uint4 v; v.x = pk[0]; v.y = pk[1]; v.z = pk[2]; v.w = pk[3];
  *reinterpret_cast<uint4*>(bfrag + (size_t)gid*8) = v;
}

// ---------------- refine: fused tt/rr 9x9 conv via MFMA ---------------------
__global__ __launch_bounds__(512) void k_refmfma(
    const float* __restrict__ srcf, float* __restrict__ dstf,
    const unsigned short* __restrict__ bfrag,
    const float* __restrict__ bt, const float* __restrict__ br)
{
  __shared__ __align__(16) unsigned short ldsA[136*64];
  const int tid  = threadIdx.x;
  const int lane = tid & 63;
  const int wv   = tid >> 6;
  const int c    = blockIdx.x >> 1;
  const int t0   = (blockIdx.x & 1) * 128;

  f32x4 acc[4];
  #pragma unroll
  for (int nt=0; nt<4; ++nt) acc[nt] = (f32x4){0.f,0.f,0.f,0.f};

  for (int kh=0; kh<9; ++kh){
    int cc = c + kh - 4;
    if (cc < 0 || cc >= 128) continue;
    for (int q = tid; q < 1088; q += 512){
      int row = q >> 3, c16 = q & 7;
      int t = t0 - 4 + row;
      uint4 v = make_uint4(0u,0u,0u,0u);
      if (t >= 0 && t < 256){
        const float* sp = srcf + ((size_t)(cc*256 + t))*64 + c16*8;
        float4 f0 = *reinterpret_cast<const float4*>(sp);
        float4 f1 = *reinterpret_cast<const float4*>(sp + 4);
        v.x = f2bf(f0.x) | (f2bf(f0.y)<<16);
        v.y = f2bf(f0.z) | (f2bf(f0.w)<<16);
        v.z = f2bf(f1.x) | (f2bf(f1.y)<<16);
        v.w = f2bf(f1.z) | (f2bf(f1.w)<<16);
      }
      *reinterpret_cast<uint4*>(&ldsA[row*64 + ((c16 ^ (row&7))*8)]) = v;
    }
    __syncthreads();
    for (int kw=0; kw<9; ++kw){
      const int p = kh*9 + kw;
      const unsigned short* bb = bfrag + (size_t)p*8*64*8;
      bf16x8 b[2][4];
      #pragma unroll
      for (int kt=0; kt<2; ++kt)
        #pragma unroll
        for (int nt=0; nt<4; ++nt)
          b[kt][nt] = *reinterpret_cast<const bf16x8*>(bb + ((kt*4+nt)*64 + lane)*8);
      const int j = wv*16 + (lane&15) + kw;
      #pragma unroll
      for (int kt=0; kt<2; ++kt){
        bf16x8 a = *reinterpret_cast<const bf16x8*>(
            &ldsA[j*64 + (((kt*4 + (lane>>4)) ^ (j&7))*8)]);
        #pragma unroll
        for (int nt=0; nt<4; ++nt)
          acc[nt] = __builtin_amdgcn_mfma_f32_16x16x32_bf16(a, b[kt][nt], acc[nt], 0,0,0);
      }
    }
    __syncthreads();
  }

  const int mbase = wv*16 + (lane>>4)*4;
  #pragma unroll
  for (int nt=0; nt<4; ++nt){
    int o = nt*16 + (lane&15);
    float bv = (o < 32) ? bt[o] : br[o-32];
    #pragma unroll
    for (int ri=0; ri<4; ++ri){
      int t = t0 + mbase + ri;
      float v = acc[nt][ri] + bv;
      v = (nt < 2) ? dfh_tanh_f(v) : (v > 0.f ? v : 0.02f*v);
      size_t idx = ((size_t)(c*256 + t))*64 + o;
      dstf[idx] = v + srcf[idx];
    }
  }
}

// ---------------- final dense (96 -> 2), fnorm scaling fused ----------------
__global__ __launch_bounds__(256) void k_final(const float* __restrict__ ref,
                                               const float* __restrict__ hft,
                                               const unsigned* __restrict__ fb,
                                               const float* __restrict__ dw,
                                               const float* __restrict__ db,
                                               float* __restrict__ out)
{
  int gid = blockIdx.x*256 + threadIdx.x;          // c*256 + t
  if (gid >= NCC*NTT) return;
  float fn = __uint_as_float(*fb);
  const float* rp = ref + gid*64;
  const float* hp = hft + gid*32;
  float s0 = db[0], s1 = db[1];
  #pragma unroll 8
  for (int f=0; f<64; ++f){ float v = rp[f]*fn; s0 += v*dw[f*2]; s1 += v*dw[f*2+1]; }
  #pragma unroll 8
  for (int f=0; f<32; ++f){ float v = hp[f]; s0 += v*dw[(64+f)*2]; s1 += v*dw[(64+f)*2+1]; }
  out[gid*2]   = s0;
  out[gid*2+1] = s1/fn;
}

extern "C" void kernel_launch(void* const* d_in, const int* in_sizes, int n_in,
                              void* d_out, int out_size, void* d_ws, size_t ws_size,
                              hipStream_t stream)
{
  const float* times    = (const float*)d_in[0];
  const float* times_in = (const float*)d_in[1];
  const float* i2nc     = (const float*)d_in[2];
  const float* i2c      = (const float*)d_in[3];
  const float* cdw  = (const float*)d_in[4];  const float* cdb  = (const float*)d_in[5];
  const float* cwy1 = (const float*)d_in[6];  const float* cby1 = (const float*)d_in[7];
  const float* cwy2 = (const float*)d_in[8];  const float* cby2 = (const float*)d_in[9];
  const float* cwz0 = (const float*)d_in[10]; const float* cbz0 = (const float*)d_in[11];
  const float* hdw  = (const float*)d_in[12]; const float* hdb  = (const float*)d_in[13];
  const float* hwy1 = (const float*)d_in[14]; const float* hby1 = (const float*)d_in[15];
  const float* hwy2 = (const float*)d_in[16]; const float* hby2 = (const float*)d_in[17];
  const float* hwz0 = (const float*)d_in[18]; const float* hbz0 = (const float*)d_in[19];
  const float* rwr  = (const float*)d_in[20]; const float* rbr  = (const float*)d_in[21];
  const float* rwt  = (const float*)d_in[22]; const float* rbt  = (const float*)d_in[23];
  const float* fdw  = (const float*)d_in[24]; const float* fdb  = (const float*)d_in[25];
  float* out = (float*)d_out;

  // ---- workspace layout (float offsets), aliased by liveness ---------------
  // FIX (R6): bfragS needs 648 frags * 64 lanes * 8 shorts = 331,776 shorts
  //           = 165,888 FLOATS (previous layout reserved only 82,944 -> the
  //           k_wconv tail overlapped refB: intra-kernel read/write race on
  //           weights + float->bf16-pair reinterpretation => NaN weights).
  //           Now placed in the dead-after-dft_e hcat region, just past refA.
  float* ws = (float*)d_ws;
  float* A   = ws;                 // 524288: x_c / cft / skip_h
  float* Bb  = ws + 524288;        // 524288: skip_c / hinp
  float* C   = ws + 1048576;       // 524288: cout / x_h
  unsigned short* xb = (unsigned short*)(ws + 1572864);   // 524288 bf16
  unsigned short* gb = (unsigned short*)(ws + 1835008);   // 262144 bf16
  float* hcat = ws + 1966080;      // 1048576 (dead after dft_e)
  float* hft  = ws + 3014656;      // 1048576 (live til final)
  unsigned short* gfrag  = (unsigned short*)(ws + 4146176); // 921600 bf16
  unsigned short* zfrag  = (unsigned short*)(ws + 4606976); // 460800 bf16
  float* refA = ws;                // [0, 2097152) overlays A,Bb,C,xb,gb,hcat-head
  unsigned short* bfragS = (unsigned short*)(ws + 2097152); // 331776 bf16 = [2097152, 2263040) floats, inside dead hcat, past refA
  float* refB = ws + 4146176;      // [4146176, 6243328) overlays gfrag,zfrag
  unsigned* fb = (unsigned*)(ws + 6243328);
  // total 6,243,329 floats ~= 25.0 MB

  float* x_c = A;  float* skp_c = Bb; float* cout = C;
  float* cft = A;  float* hinp  = Bb; float* x_h  = C; float* skp_h = A;

  static const int DILS[15] = {1,2,3,4,6,8,10,12,14,16,18,20,24,28,32};

  // ---- pack all 90 layers' wave weights into fragment order ----
  k_wpack<<<675,256,0,stream>>>(cwy1, cwy2, cwz0, hwy1, hwy2, hwz0, gfrag, zfrag);

  // ---- c fidnet layer (H=256 t, W=128 c) ----
  k_build_c<<<128,256,0,stream>>>(times, times_in, i2nc, i2c, cdw, cdb, x_c, xb, skp_c);
  for (int i=0; i<45; ++i){
    int dil = DILS[i % 15];
    k_gate_mfma<128><<<256,512,0,stream>>>(xb, gb, gfrag + (size_t)i*10240,
                                           cby1 + i*8, cby2 + i*8, 256, dil);
    k_zres_mfma<128><<<256,512,0,stream>>>(gb, x_c, xb, skp_c, zfrag + (size_t)i*5120,
                                           cbz0 + i*16, 256);
  }
  k_dtanh_t<<<128,256,0,stream>>>(skp_c, cout);

  // ---- spectral block ----
  k_dft_c1<<<2048,256,0,stream>>>(cout, cft);
  k_dft_c2<<<1024,256,0,stream>>>(cft, times, hinp);

  // ---- h fidnet layer (H=128 c, W=256 t) ----
  k_build_h<<<128,256,0,stream>>>(hinp, hdw, hdb, x_h, xb, skp_h);
  for (int i=0; i<45; ++i){
    int dil = DILS[i % 15];
    k_gate_mfma<256><<<256,512,0,stream>>>(xb, gb, gfrag + (size_t)(45+i)*10240,
                                           hby1 + i*8, hby2 + i*8, 128, dil);
    k_zres_mfma<256><<<256,512,0,stream>>>(gb, x_h, xb, skp_h, zfrag + (size_t)(45+i)*5120,
                                           hbz0 + i*16, 128);
  }
  k_houtcat<<<128,256,0,stream>>>(skp_h, hinp, hcat, fb);

  // ---- stage E DFT + fnorm ----
  k_dft_e<<<4096,256,0,stream>>>(hcat, hft);
  k_fnorm<<<1024,256,0,stream>>>(hft, fb, 1048576);

  // ---- refine: 4 steps, fused tt/rr MFMA conv ----
  k_refinit<<<8192,256,0,stream>>>(hft, fb, refA);
  float* rsrc = refA; float* rdst = refB;
  for (int i=0; i<4; ++i){
    k_wconv<<<162,256,0,stream>>>(rwt + i*165888, rwr + i*165888, bfragS);
    k_refmfma<<<256,512,0,stream>>>(rsrc, rdst, bfragS, rbt + i*32, rbr + i*32);
    float* tmp = rsrc; rsrc = rdst; rdst = tmp;
  }

  // ---- final dense ----
  k_final<<<128,256,0,stream>>>(rsrc, hft, fb, fdw, fdb, out);
}